// Round 2
// baseline (330.855 us; speedup 1.0000x reference)
//
#include <hip/hip_runtime.h>
#include <hip/hip_bf16.h>

// MoE fused kernel for MI355X (gfx950).
// out[t,o] = sum_e w[t,e] * (relu(x[t]@W1[e]^T) @ W2[e]^T),
// w = softmax_e(mask( relu(x@sg1^T)@(gate_w@sg_w2)^T + x@gate_w^T ))
//
// R2: BM=64, 4 waves/block, 1024 blocks -> 4 blocks/CU (vs 2) so barrier
// drains overlap across independent blocks. No split-K. Coalesced f32x4
// output via LDS re-stage.

typedef float f32x4 __attribute__((ext_vector_type(4)));
typedef short bf16x8 __attribute__((ext_vector_type(8)));

static __device__ __forceinline__ short f2bs(float f) {
  union { __hip_bfloat16 b; short s; } u;
  u.b = __float2bfloat16(f);
  return u.s;
}

// ws layout (shorts):
//   [0,       262144)  W1p  packed frags: (e*64 + ntile*4 + k)*512 + lane*8 + j
//   [262144,  524288)  W2p  packed frags: (e*64 + otile*8 + kstep)*512 + lane*8 + j
//   [524288,  526336)  sg1b [16][128]
//   [526336,  527360)  gwb  [8][128]
//   [527360,  527488)  gcb  [8][16]   (= gate_w @ sg_w2)

__global__ void prep_kernel(const float* __restrict__ sg_w1,
                            const float* __restrict__ sg_w2,
                            const float* __restrict__ gate_w,
                            const float* __restrict__ exp_w1,
                            const float* __restrict__ exp_w2,
                            short* __restrict__ ws_s) {
  int idx = blockIdx.x * 256 + threadIdx.x;
  if (idx < 262144) {
    int e = idx >> 15, rem = idx & 32767;
    int frag = rem >> 9, lane = (rem >> 3) & 63, j = rem & 7;
    int hid = (frag >> 2) * 16 + (lane & 15);
    int k   = (frag & 3) * 32 + (lane >> 4) * 8 + j;
    ws_s[idx] = f2bs(exp_w1[(e * 256 + hid) * 128 + k]);
  } else if (idx < 524288) {
    int i2 = idx - 262144;
    int e = i2 >> 15, rem = i2 & 32767;
    int frag = rem >> 9, lane = (rem >> 3) & 63, j = rem & 7;
    int o = (frag >> 3) * 16 + (lane & 15);
    int h = (frag & 7) * 32 + (lane >> 4) * 8 + j;
    ws_s[idx] = f2bs(exp_w2[(e * 128 + o) * 256 + h]);
  } else if (idx < 526336) {
    ws_s[idx] = f2bs(sg_w1[idx - 524288]);
  } else if (idx < 527360) {
    ws_s[idx] = f2bs(gate_w[idx - 526336]);
  } else if (idx < 527488) {
    int i = idx - 527360, e = i >> 4, j = i & 15;
    float acc = 0.f;
    for (int k = 0; k < 128; ++k) acc += gate_w[e * 128 + k] * sg_w2[k * 16 + j];
    ws_s[idx] = f2bs(acc);
  }
}

__global__ __launch_bounds__(256, 4) void moe_kernel(
    const float* __restrict__ x, const int* __restrict__ active,
    const short* __restrict__ ws_s, float* __restrict__ out) {
  __shared__ __align__(16) unsigned char smem[33792];

  const short* W1p  = ws_s;
  const short* W2p  = ws_s + 262144;
  const short* sg1b = ws_s + 524288;
  const short* gwb  = ws_s + 526336;
  const short* gcb  = ws_s + 527360;

  const int tid  = threadIdx.x;
  const int lane = tid & 63;
  const int wid  = tid >> 6;      // 0..3
  const int l15  = lane & 15;
  const int lg   = lane >> 4;     // 0..3
  const int tok0 = blockIdx.x * 64;

  // gate overlay region (inside the H buffer, freed before expert loop)
  short* Ul   = (short*)(smem);           // [64][40] bf16, cols 16..31 zero
  short* sg1l = (short*)(smem + 5120);    // [16][136]
  short* gwl  = (short*)(smem + 9472);    // [16][136], rows 8..15 zero
  short* gcl  = (short*)(smem + 13824);   // [16][40],  pads zero

  for (int i = tid; i < 3776; i += 256) ((int*)smem)[i] = 0;
  __syncthreads();
  for (int i = tid; i < 2048; i += 256) sg1l[(i >> 7) * 136 + (i & 127)] = sg1b[i];
  for (int i = tid; i < 1024; i += 256) gwl[(i >> 7) * 136 + (i & 127)] = gwb[i];
  if (tid < 128) gcl[(tid >> 4) * 40 + (tid & 15)] = gcb[tid];

  // ---- X fragments (A-operand), resident for the whole kernel ----
  bf16x8 xf[4][4];
  {
    int trow = tok0 + l15;
#pragma unroll
    for (int m = 0; m < 4; ++m) {
      const float* xr = x + (size_t)(trow + m * 16) * 128;
#pragma unroll
      for (int k = 0; k < 4; ++k) {
        int c = k * 32 + lg * 8;
        float4 a = *(const float4*)(xr + c);
        float4 b = *(const float4*)(xr + c + 4);
        bf16x8 v;
        v[0] = f2bs(a.x); v[1] = f2bs(a.y); v[2] = f2bs(a.z); v[3] = f2bs(a.w);
        v[4] = f2bs(b.x); v[5] = f2bs(b.y); v[6] = f2bs(b.z); v[7] = f2bs(b.w);
        xf[m][k] = v;
      }
    }
  }
  __syncthreads();

  // ---- gate: scores = relu(X@sg1^T)@gcomb^T + X@gw^T ; masked softmax ----
  f32x4 wreg[4];
  {
    bf16x8 bfr[4];
#pragma unroll
    for (int k = 0; k < 4; ++k)
      bfr[k] = *(const bf16x8*)(sg1l + l15 * 136 + k * 32 + lg * 8);
#pragma unroll
    for (int m = 0; m < 4; ++m) {
      f32x4 acc = {0.f, 0.f, 0.f, 0.f};
#pragma unroll
      for (int k = 0; k < 4; ++k)
        acc = __builtin_amdgcn_mfma_f32_16x16x32_bf16(xf[m][k], bfr[k], acc, 0, 0, 0);
      if (wid == 0) {
#pragma unroll
        for (int r = 0; r < 4; ++r) {
          int tl = m * 16 + lg * 4 + r;
          Ul[tl * 40 + l15] = f2bs(fmaxf(acc[r], 0.f));
        }
      }
    }
#pragma unroll
    for (int k = 0; k < 4; ++k)
      bfr[k] = *(const bf16x8*)(gwl + l15 * 136 + k * 32 + lg * 8);
    f32x4 sc[4];
#pragma unroll
    for (int m = 0; m < 4; ++m) {
      f32x4 acc = {0.f, 0.f, 0.f, 0.f};
#pragma unroll
      for (int k = 0; k < 4; ++k)
        acc = __builtin_amdgcn_mfma_f32_16x16x32_bf16(xf[m][k], bfr[k], acc, 0, 0, 0);
      sc[m] = acc;
    }
    __syncthreads();  // Ul visible to all waves
    bf16x8 gcf = *(const bf16x8*)(gcl + l15 * 40 + lg * 8);
#pragma unroll
    for (int m = 0; m < 4; ++m) {
      int tr = m * 16 + l15;
      bf16x8 uf = *(const bf16x8*)(Ul + tr * 40 + lg * 8);
      sc[m] = __builtin_amdgcn_mfma_f32_16x16x32_bf16(uf, gcf, sc[m], 0, 0, 0);
    }
    int b = tok0 >> 12;
    float am = (l15 < 8 && active[b * 8 + l15] != 0) ? 0.f : -3.0e38f;
#pragma unroll
    for (int m = 0; m < 4; ++m) {
      f32x4 w4;
#pragma unroll
      for (int r = 0; r < 4; ++r) {
        float s = sc[m][r] + am;
        float mx = s;
        mx = fmaxf(mx, __shfl_xor(mx, 1));
        mx = fmaxf(mx, __shfl_xor(mx, 2));
        mx = fmaxf(mx, __shfl_xor(mx, 4));
        float p = __expf(s - mx);
        float su = p;
        su += __shfl_xor(su, 1);
        su += __shfl_xor(su, 2);
        su += __shfl_xor(su, 4);
        w4[r] = p / su;
      }
      wreg[m] = w4;
    }
  }
  __syncthreads();  // gate overlay done; smem becomes H [64][256] bf16 (swizzled)

  f32x4 acc2[4][2];
#pragma unroll
  for (int m = 0; m < 4; ++m)
#pragma unroll
    for (int n = 0; n < 2; ++n)
      acc2[m][n] = {0.f, 0.f, 0.f, 0.f};

  for (int e = 0; e < 8; ++e) {
    float wv[4][4];
#pragma unroll
    for (int m = 0; m < 4; ++m)
#pragma unroll
      for (int r = 0; r < 4; ++r)
        wv[m][r] = __shfl(wreg[m][r], (lane & 48) | e);

    // ---- G1: H = relu(X @ W1e^T) * w; wave covers [64 tok][64 hid] ----
    const short* w1e = W1p + (e * 64 + wid * 16) * 512 + lane * 8;
#pragma unroll
    for (int n = 0; n < 4; ++n) {
      f32x4 a1[4];
#pragma unroll
      for (int m = 0; m < 4; ++m) a1[m] = {0.f, 0.f, 0.f, 0.f};
#pragma unroll
      for (int k = 0; k < 4; ++k) {
        bf16x8 wf = *(const bf16x8*)(w1e + (n * 4 + k) * 512);
#pragma unroll
        for (int m = 0; m < 4; ++m)
          a1[m] = __builtin_amdgcn_mfma_f32_16x16x32_bf16(xf[m][k], wf, a1[m], 0, 0, 0);
      }
      int h2 = (wid * 64 + n * 16 + l15) * 2;
#pragma unroll
      for (int m = 0; m < 4; ++m) {
#pragma unroll
        for (int r = 0; r < 4; ++r) {
          int tl = m * 16 + lg * 4 + r;
          float v = fmaxf(a1[m][r], 0.f) * wv[m][r];
          *(short*)(smem + tl * 512 + (h2 ^ ((tl & 7) << 4))) = f2bs(v);
        }
      }
    }
    __syncthreads();

    // ---- G2: acc2 += H @ W2e^T; wave covers [64 tok][32 out], K=256 ----
#pragma unroll
    for (int kstep = 0; kstep < 8; ++kstep) {
      bf16x8 hf[4];
#pragma unroll
      for (int m = 0; m < 4; ++m) {
        int tl = m * 16 + l15;
        int h2 = (kstep * 32 + lg * 8) * 2;
        hf[m] = *(const bf16x8*)(smem + tl * 512 + (h2 ^ ((tl & 7) << 4)));
      }
#pragma unroll
      for (int n2 = 0; n2 < 2; ++n2) {
        bf16x8 wf = *(const bf16x8*)(W2p + (e * 64 + (wid * 2 + n2) * 8 + kstep) * 512 + lane * 8);
#pragma unroll
        for (int m = 0; m < 4; ++m)
          acc2[m][n2] = __builtin_amdgcn_mfma_f32_16x16x32_bf16(hf[m], wf, acc2[m][n2], 0, 0, 0);
      }
    }
    __syncthreads();
  }

  // ---- epilogue: stage to LDS f32 [64][132], then coalesced 16B stores ----
  float* st = (float*)smem;
#pragma unroll
  for (int m = 0; m < 4; ++m)
#pragma unroll
    for (int n2 = 0; n2 < 2; ++n2)
#pragma unroll
      for (int r = 0; r < 4; ++r) {
        int tl = m * 16 + lg * 4 + r;
        int o = wid * 32 + n2 * 16 + l15;
        st[tl * 132 + o] = acc2[m][n2][r];
      }
  __syncthreads();
  {
    float* orow = out + (size_t)tok0 * 128;
#pragma unroll
    for (int i = 0; i < 8; ++i) {
      int g = i * 256 + tid;
      int row = g >> 5, c4 = g & 31;
      *(float4*)(orow + row * 128 + c4 * 4) = *(const float4*)(st + row * 132 + c4 * 4);
    }
  }
  if (blockIdx.x == 0 && tid == 0) out[8388608] = 0.0f;  // aux_loss
}

extern "C" void kernel_launch(void* const* d_in, const int* in_sizes, int n_in,
                              void* d_out, int out_size, void* d_ws, size_t ws_size,
                              hipStream_t stream) {
  const float* x      = (const float*)d_in[0];
  const int*   act    = (const int*)d_in[1];
  const float* sg_w1  = (const float*)d_in[2];
  const float* sg_w2  = (const float*)d_in[3];
  const float* gate_w = (const float*)d_in[4];
  const float* exp_w1 = (const float*)d_in[5];
  const float* exp_w2 = (const float*)d_in[6];
  short* ws_s = (short*)d_ws;
  float* out = (float*)d_out;

  prep_kernel<<<2061, 256, 0, stream>>>(sg_w1, sg_w2, gate_w, exp_w1, exp_w2, ws_s);
  moe_kernel<<<1024, 256, 0, stream>>>(x, act, ws_s, out);
}

// Round 5
// 103.262 us; speedup vs baseline: 3.2040x; 3.2040x over previous
//
#include <hip/hip_runtime.h>
#include <hip/hip_bf16.h>

// MoE fused kernel for MI355X (gfx950) — R5: R4 + gate-LDS race fix.
// out[t,o] = sum_e w[t,e] * (relu(x[t]@W1[e]^T) @ W2[e]^T),
// w = softmax_e(mask( relu(x@sg1^T)@(gate_w@sg_w2)^T + x@gate_w^T ))
//
// Each wave owns 32 tokens; expert loop is barrier-free all-register.
// G1 swapped: mfma(W1,X) -> D[hid][token]: lane holds H for its own token.
// W2 is prep-packed with a permuted k-order matching G1's output layout, so
// the G1 accumulator -> relu*w -> bf16 pack IS a legal G2 B-fragment.
// G2 swapped: mfma(W2,H) -> D[out][token] -> direct coalesced f32x4 stores.
//
// R5 fix: the gate's U tile is a CROSS-LANE LDS exchange (written at rows
// lg*4+r, read at rows l15) — needs __syncthreads() (R3/R4 raced; R2 with
// barriers passed at 3.9e-3; race corrupted gate weights -> absmax 7.1e-2).

typedef float f32x4 __attribute__((ext_vector_type(4)));
typedef short bf16x8 __attribute__((ext_vector_type(8)));

static __device__ __forceinline__ short f2bs(float f) {
  union { __hip_bfloat16 b; short s; } u;
  u.b = __float2bfloat16(f);
  return u.s;
}

// ws layout (shorts):
//  [0,262144)       W1p : (e*64 + ks*8 + n*4 + kx)*512 + lane*8 + j
//                         = W1[e][ks*32+n*16+l15][kx*32+lg*8+j]
//  [262144,524288)  W2p : (e*64 + o*8 + ks)*512 + lane*8 + j
//                         = W2[e][o*16+l15][ks*32 + perm(lg,j)]
//                           perm(lg,j) = j<4 ? lg*4+j : 16+lg*4+(j-4)
//  [524288,526336)  sg1p: k*512 + lane*8 + j = sg_w1[l15][k*32+lg*8+j]
//  [526336,528384)  gwp : k*512 + lane*8 + j = l15<8 ? gate_w[l15][...] : 0
//  [528384,528896)  gcp : lane*8 + j = (l15<8 && lg*8+j<16) ? gc[l15][lg*8+j] : 0
//                         gc = gate_w @ sg_w2  [8,16]

__global__ void prep_kernel(const float* __restrict__ sg_w1,
                            const float* __restrict__ sg_w2,
                            const float* __restrict__ gate_w,
                            const float* __restrict__ exp_w1,
                            const float* __restrict__ exp_w2,
                            short* __restrict__ ws_s) {
  int idx = blockIdx.x * 256 + threadIdx.x;
  if (idx < 262144) {
    int e = idx >> 15, rem = idx & 32767;
    int frag = rem >> 9, lane = (rem >> 3) & 63, j = rem & 7;
    int hid = (frag >> 2) * 16 + (lane & 15);
    int k   = (frag & 3) * 32 + (lane >> 4) * 8 + j;
    ws_s[idx] = f2bs(exp_w1[(e * 256 + hid) * 128 + k]);
  } else if (idx < 524288) {
    int i2 = idx - 262144;
    int e = i2 >> 15, rem = i2 & 32767;
    int frag = rem >> 9, lane = (rem >> 3) & 63, j = rem & 7;
    int lg = lane >> 4, l15 = lane & 15;
    int o  = (frag >> 3) * 16 + l15;
    int ks = frag & 7;
    int h  = ks * 32 + (j < 4 ? lg * 4 + j : 16 + lg * 4 + (j - 4));
    ws_s[idx] = f2bs(exp_w2[(e * 128 + o) * 256 + h]);
  } else if (idx < 526336) {
    int i3 = idx - 524288;
    int k = i3 >> 9, lane = (i3 >> 3) & 63, j = i3 & 7;
    int lg = lane >> 4, l15 = lane & 15;
    ws_s[idx] = f2bs(sg_w1[l15 * 128 + k * 32 + lg * 8 + j]);
  } else if (idx < 528384) {
    int i4 = idx - 526336;
    int k = i4 >> 9, lane = (i4 >> 3) & 63, j = i4 & 7;
    int lg = lane >> 4, l15 = lane & 15;
    ws_s[idx] = (l15 < 8) ? f2bs(gate_w[l15 * 128 + k * 32 + lg * 8 + j]) : (short)0;
  } else if (idx < 528896) {
    int i5 = idx - 528384;
    int lane = (i5 >> 3) & 63, j = i5 & 7;
    int lg = lane >> 4, l15 = lane & 15;
    int kk = lg * 8 + j;
    if (l15 < 8 && kk < 16) {
      float acc = 0.f;
      for (int d = 0; d < 128; ++d) acc += gate_w[l15 * 128 + d] * sg_w2[d * 16 + kk];
      ws_s[idx] = f2bs(acc);
    } else {
      ws_s[idx] = 0;
    }
  }
}

__global__ __launch_bounds__(256, 2) void moe_kernel(
    const float* __restrict__ x, const int* __restrict__ active,
    const short* __restrict__ ws_s, float* __restrict__ out) {
  __shared__ short Ul[4][1280];  // per-wave [32][40] bf16 U tile (cols 16+ zero)

  const short* W1p  = ws_s;
  const short* W2p  = ws_s + 262144;
  const short* sg1p = ws_s + 524288;
  const short* gwp  = ws_s + 526336;
  const short* gcp  = ws_s + 528384;

  const int tid  = threadIdx.x;
  const int lane = tid & 63;
  const int wid  = tid >> 6;     // 0..3
  const int l15  = lane & 15;
  const int lg   = lane >> 4;    // 0..3
  const int tokw = blockIdx.x * 128 + wid * 32;

  short* Ulw = &Ul[wid][0];
  for (int i = lane; i < 640; i += 64) ((int*)Ulw)[i] = 0;
  __syncthreads();  // zero-init visible before U-writes (cross-lane WAW)

  // ---- X fragments: lane holds row=token(l15), k=lg*8+j ----
  bf16x8 xf[2][4];
  {
    int trow = tokw + l15;
#pragma unroll
    for (int m = 0; m < 2; ++m) {
      const float* xr = x + (size_t)(trow + m * 16) * 128;
#pragma unroll
      for (int k = 0; k < 4; ++k) {
        int c = k * 32 + lg * 8;
        float4 a = *(const float4*)(xr + c);
        float4 b = *(const float4*)(xr + c + 4);
        bf16x8 v;
        v[0] = f2bs(a.x); v[1] = f2bs(a.y); v[2] = f2bs(a.z); v[3] = f2bs(a.w);
        v[4] = f2bs(b.x); v[5] = f2bs(b.y); v[6] = f2bs(b.z); v[7] = f2bs(b.w);
        xf[m][k] = v;
      }
    }
  }

  // ---- gate ----
  f32x4 wreg[2];
  {
    bf16x8 sgf[4], gwf[4];
#pragma unroll
    for (int k = 0; k < 4; ++k) {
      sgf[k] = *(const bf16x8*)(sg1p + k * 512 + lane * 8);
      gwf[k] = *(const bf16x8*)(gwp  + k * 512 + lane * 8);
    }
    // U = relu(X @ sg1^T): D[token][sghid] -> write bf16 to Ulw[token][sghid]
#pragma unroll
    for (int m = 0; m < 2; ++m) {
      f32x4 acc = {0.f, 0.f, 0.f, 0.f};
#pragma unroll
      for (int k = 0; k < 4; ++k)
        acc = __builtin_amdgcn_mfma_f32_16x16x32_bf16(xf[m][k], sgf[k], acc, 0, 0, 0);
#pragma unroll
      for (int r = 0; r < 4; ++r)
        Ulw[(m * 16 + lg * 4 + r) * 40 + l15] = f2bs(fmaxf(acc[r], 0.f));
    }
    // sc = X @ gate_w^T : D[token][e]
    f32x4 sc[2];
#pragma unroll
    for (int m = 0; m < 2; ++m) {
      f32x4 acc = {0.f, 0.f, 0.f, 0.f};
#pragma unroll
      for (int k = 0; k < 4; ++k)
        acc = __builtin_amdgcn_mfma_f32_16x16x32_bf16(xf[m][k], gwf[k], acc, 0, 0, 0);
      sc[m] = acc;
    }
    __syncthreads();  // U-writes (rows lg*4+r) visible to uf-reads (rows l15)
    // sc += U @ gc^T (K padded to 32 with zeros)
    bf16x8 gcf = *(const bf16x8*)(gcp + lane * 8);
#pragma unroll
    for (int m = 0; m < 2; ++m) {
      bf16x8 uf = *(const bf16x8*)(Ulw + (m * 16 + l15) * 40 + lg * 8);
      sc[m] = __builtin_amdgcn_mfma_f32_16x16x32_bf16(uf, gcf, sc[m], 0, 0, 0);
    }
    // masked softmax over e (lane l15 = e)
    int b = tokw >> 12;
    float am = (l15 < 8 && active[b * 8 + l15] != 0) ? 0.f : -3.0e38f;
#pragma unroll
    for (int m = 0; m < 2; ++m) {
      f32x4 w4;
#pragma unroll
      for (int r = 0; r < 4; ++r) {
        float s = sc[m][r] + am;
        float mx = s;
        mx = fmaxf(mx, __shfl_xor(mx, 1));
        mx = fmaxf(mx, __shfl_xor(mx, 2));
        mx = fmaxf(mx, __shfl_xor(mx, 4));
        float p = __expf(s - mx);
        float su = p;
        su += __shfl_xor(su, 1);
        su += __shfl_xor(su, 2);
        su += __shfl_xor(su, 4);
        w4[r] = p / su;
      }
      wreg[m] = w4;
    }
  }

  // ---- expert loop: zero barriers, all-register dataflow ----
  f32x4 acc2[2][8];
#pragma unroll
  for (int m = 0; m < 2; ++m)
#pragma unroll
    for (int o = 0; o < 8; ++o)
      acc2[m][o] = {0.f, 0.f, 0.f, 0.f};

  for (int e = 0; e < 8; ++e) {
    // wv[m] = w[token=l15 (+m*16)][e]; source lane ((l15>>2)<<4)|e, reg l15&3
    float wv0, wv1;
    {
      int srcb = ((l15 >> 2) << 4) | e;
      int rp = l15 & 3;
      float q0 = __shfl(wreg[0][0], srcb), q1 = __shfl(wreg[0][1], srcb);
      float q2 = __shfl(wreg[0][2], srcb), q3 = __shfl(wreg[0][3], srcb);
      float lo = (rp & 1) ? q1 : q0, hi = (rp & 1) ? q3 : q2;
      wv0 = (rp & 2) ? hi : lo;
      q0 = __shfl(wreg[1][0], srcb); q1 = __shfl(wreg[1][1], srcb);
      q2 = __shfl(wreg[1][2], srcb); q3 = __shfl(wreg[1][3], srcb);
      lo = (rp & 1) ? q1 : q0; hi = (rp & 1) ? q3 : q2;
      wv1 = (rp & 2) ? hi : lo;
    }
    const short* w1e = W1p + e * 32768 + lane * 8;
    const short* w2e = W2p + e * 32768 + lane * 8;
#pragma unroll 2
    for (int ks = 0; ks < 8; ++ks) {
      // G1: D[hid][token] for 32-hid chunk ks (2 hid-tiles x K=128)
      bf16x8 w1f[8];
#pragma unroll
      for (int i = 0; i < 8; ++i)  // i = n*4 + kx
        w1f[i] = *(const bf16x8*)(w1e + (ks * 8 + i) * 512);
      f32x4 a1[2][2];
#pragma unroll
      for (int m = 0; m < 2; ++m)
#pragma unroll
        for (int n = 0; n < 2; ++n) {
          f32x4 acc = {0.f, 0.f, 0.f, 0.f};
#pragma unroll
          for (int kx = 0; kx < 4; ++kx)
            acc = __builtin_amdgcn_mfma_f32_16x16x32_bf16(w1f[n * 4 + kx], xf[m][kx], acc, 0, 0, 0);
          a1[m][n] = acc;
        }
      // pack: lane's 8 H values (token=l15) -> G2 B-frag in permuted k-order
      bf16x8 hB[2];
#pragma unroll
      for (int m = 0; m < 2; ++m) {
        float wvm = m ? wv1 : wv0;
        bf16x8 h;
#pragma unroll
        for (int r = 0; r < 4; ++r) {
          h[r]     = f2bs(fmaxf(a1[m][0][r], 0.f) * wvm);
          h[r + 4] = f2bs(fmaxf(a1[m][1][r], 0.f) * wvm);
        }
        hB[m] = h;
      }
      // G2: acc2[m][o] += mfma(W2frag[o][ks], hB[m])  (D[out][token])
#pragma unroll
      for (int o = 0; o < 8; ++o) {
        bf16x8 w2f = *(const bf16x8*)(w2e + (o * 8 + ks) * 512);
#pragma unroll
        for (int m = 0; m < 2; ++m)
          acc2[m][o] = __builtin_amdgcn_mfma_f32_16x16x32_bf16(w2f, hB[m], acc2[m][o], 0, 0, 0);
      }
    }
  }

  // ---- direct stores: lane holds out = o*16+lg*4..+3, token = l15 (+m*16) ----
#pragma unroll
  for (int m = 0; m < 2; ++m)
#pragma unroll
    for (int o = 0; o < 8; ++o)
      *(f32x4*)(out + (size_t)(tokw + m * 16 + l15) * 128 + o * 16 + lg * 4) = acc2[m][o];

  if (blockIdx.x == 0 && tid == 0) out[8388608] = 0.0f;  // aux_loss
}

extern "C" void kernel_launch(void* const* d_in, const int* in_sizes, int n_in,
                              void* d_out, int out_size, void* d_ws, size_t ws_size,
                              hipStream_t stream) {
  const float* x      = (const float*)d_in[0];
  const int*   act    = (const int*)d_in[1];
  const float* sg_w1  = (const float*)d_in[2];
  const float* sg_w2  = (const float*)d_in[3];
  const float* gate_w = (const float*)d_in[4];
  const float* exp_w1 = (const float*)d_in[5];
  const float* exp_w2 = (const float*)d_in[6];
  short* ws_s = (short*)d_ws;
  float* out = (float*)d_out;

  prep_kernel<<<2066, 256, 0, stream>>>(sg_w1, sg_w2, gate_w, exp_w1, exp_w2, ws_s);
  moe_kernel<<<512, 256, 0, stream>>>(x, act, ws_s, out);
}

// Round 6
// 82.658 us; speedup vs baseline: 4.0027x; 1.2493x over previous
//
#include <hip/hip_runtime.h>
#include <hip/hip_bf16.h>

// MoE fused kernel for MI355X (gfx950) — R6: 64 tokens/wave, register
// double-buffered weight stream, 1 wave/SIMD with 512-VGPR budget.
// out[t,o] = sum_e w[t,e] * (relu(x[t]@W1[e]^T) @ W2[e]^T),
// w = softmax_e(mask( relu(x@sg1^T)@(gate_w@sg_w2)^T + x@gate_w^T ))
//
// Expert loop is barrier-free all-register (verified R5):
// G1 swapped: mfma(W1,X) -> D[hid][token]: lane holds H for its own token.
// W2 prep-packed in permuted k-order so the G1 accumulator -> relu*w -> bf16
// pack IS a legal G2 B-fragment. G2 swapped: mfma(W2,H) -> D[out][token]
// -> direct coalesced f32x4 stores.
// R6 change: m=2 -> m=4 (64 tok/wave) halves the per-token weight traffic
// (1 GB total L2 stream instead of 2 GB); explicit even/odd register
// double-buffer on the 16 weight fragments per 32-hid chunk hides L2 latency
// under the 64-MFMA compute cluster.

typedef float f32x4 __attribute__((ext_vector_type(4)));
typedef short bf16x8 __attribute__((ext_vector_type(8)));

static __device__ __forceinline__ short f2bs(float f) {
  union { __hip_bfloat16 b; short s; } u;
  u.b = __float2bfloat16(f);
  return u.s;
}

// ws layout (shorts):
//  [0,262144)       W1p : (e*64 + ks*8 + n*4 + kx)*512 + lane*8 + j
//                         = W1[e][ks*32+n*16+l15][kx*32+lg*8+j]
//  [262144,524288)  W2p : (e*64 + o*8 + ks)*512 + lane*8 + j
//                         = W2[e][o*16+l15][ks*32 + perm(lg,j)]
//                           perm(lg,j) = j<4 ? lg*4+j : 16+lg*4+(j-4)
//  [524288,526336)  sg1p: k*512 + lane*8 + j = sg_w1[l15][k*32+lg*8+j]
//  [526336,528384)  gwp : k*512 + lane*8 + j = l15<8 ? gate_w[l15][...] : 0
//  [528384,528896)  gcp : lane*8 + j = (l15<8 && lg*8+j<16) ? gc[l15][lg*8+j] : 0
//                         gc = gate_w @ sg_w2  [8,16]

__global__ void prep_kernel(const float* __restrict__ sg_w1,
                            const float* __restrict__ sg_w2,
                            const float* __restrict__ gate_w,
                            const float* __restrict__ exp_w1,
                            const float* __restrict__ exp_w2,
                            short* __restrict__ ws_s) {
  int idx = blockIdx.x * 256 + threadIdx.x;
  if (idx < 262144) {
    int e = idx >> 15, rem = idx & 32767;
    int frag = rem >> 9, lane = (rem >> 3) & 63, j = rem & 7;
    int hid = (frag >> 2) * 16 + (lane & 15);
    int k   = (frag & 3) * 32 + (lane >> 4) * 8 + j;
    ws_s[idx] = f2bs(exp_w1[(e * 256 + hid) * 128 + k]);
  } else if (idx < 524288) {
    int i2 = idx - 262144;
    int e = i2 >> 15, rem = i2 & 32767;
    int frag = rem >> 9, lane = (rem >> 3) & 63, j = rem & 7;
    int lg = lane >> 4, l15 = lane & 15;
    int o  = (frag >> 3) * 16 + l15;
    int ks = frag & 7;
    int h  = ks * 32 + (j < 4 ? lg * 4 + j : 16 + lg * 4 + (j - 4));
    ws_s[idx] = f2bs(exp_w2[(e * 128 + o) * 256 + h]);
  } else if (idx < 526336) {
    int i3 = idx - 524288;
    int k = i3 >> 9, lane = (i3 >> 3) & 63, j = i3 & 7;
    int lg = lane >> 4, l15 = lane & 15;
    ws_s[idx] = f2bs(sg_w1[l15 * 128 + k * 32 + lg * 8 + j]);
  } else if (idx < 528384) {
    int i4 = idx - 526336;
    int k = i4 >> 9, lane = (i4 >> 3) & 63, j = i4 & 7;
    int lg = lane >> 4, l15 = lane & 15;
    ws_s[idx] = (l15 < 8) ? f2bs(gate_w[l15 * 128 + k * 32 + lg * 8 + j]) : (short)0;
  } else if (idx < 528896) {
    int i5 = idx - 528384;
    int lane = (i5 >> 3) & 63, j = i5 & 7;
    int lg = lane >> 4, l15 = lane & 15;
    int kk = lg * 8 + j;
    if (l15 < 8 && kk < 16) {
      float acc = 0.f;
      for (int d = 0; d < 128; ++d) acc += gate_w[l15 * 128 + d] * sg_w2[d * 16 + kk];
      ws_s[idx] = f2bs(acc);
    } else {
      ws_s[idx] = 0;
    }
  }
}

__global__ __launch_bounds__(256, 1) void moe_kernel(
    const float* __restrict__ x, const int* __restrict__ active,
    const short* __restrict__ ws_s, float* __restrict__ out) {
  __shared__ short Ul[4][2560];  // per-wave [64][40] bf16 U tile (cols 16+ zero)

  const short* W1p  = ws_s;
  const short* W2p  = ws_s + 262144;
  const short* sg1p = ws_s + 524288;
  const short* gwp  = ws_s + 526336;
  const short* gcp  = ws_s + 528384;

  const int tid  = threadIdx.x;
  const int lane = tid & 63;
  const int wid  = tid >> 6;     // 0..3
  const int l15  = lane & 15;
  const int lg   = lane >> 4;    // 0..3
  const int tokw = blockIdx.x * 256 + wid * 64;

  short* Ulw = &Ul[wid][0];
  for (int i = lane; i < 1280; i += 64) ((int*)Ulw)[i] = 0;
  __syncthreads();  // zero-init visible before U-writes (cross-lane WAW)

  // ---- X fragments: lane holds row=token(l15 + m*16), k=lg*8+j ----
  bf16x8 xf[4][4];
  {
    int trow = tokw + l15;
#pragma unroll
    for (int m = 0; m < 4; ++m) {
      const float* xr = x + (size_t)(trow + m * 16) * 128;
#pragma unroll
      for (int k = 0; k < 4; ++k) {
        int c = k * 32 + lg * 8;
        float4 a = *(const float4*)(xr + c);
        float4 b = *(const float4*)(xr + c + 4);
        bf16x8 v;
        v[0] = f2bs(a.x); v[1] = f2bs(a.y); v[2] = f2bs(a.z); v[3] = f2bs(a.w);
        v[4] = f2bs(b.x); v[5] = f2bs(b.y); v[6] = f2bs(b.z); v[7] = f2bs(b.w);
        xf[m][k] = v;
      }
    }
  }

  // ---- gate ----
  f32x4 wreg[4];
  {
    bf16x8 sgf[4], gwf[4];
#pragma unroll
    for (int k = 0; k < 4; ++k) {
      sgf[k] = *(const bf16x8*)(sg1p + k * 512 + lane * 8);
      gwf[k] = *(const bf16x8*)(gwp  + k * 512 + lane * 8);
    }
    // U = relu(X @ sg1^T): D[token][sghid] -> write bf16 to Ulw[token][sghid]
#pragma unroll
    for (int m = 0; m < 4; ++m) {
      f32x4 acc = {0.f, 0.f, 0.f, 0.f};
#pragma unroll
      for (int k = 0; k < 4; ++k)
        acc = __builtin_amdgcn_mfma_f32_16x16x32_bf16(xf[m][k], sgf[k], acc, 0, 0, 0);
#pragma unroll
      for (int r = 0; r < 4; ++r)
        Ulw[(m * 16 + lg * 4 + r) * 40 + l15] = f2bs(fmaxf(acc[r], 0.f));
    }
    // sc = X @ gate_w^T : D[token][e]
    f32x4 sc[4];
#pragma unroll
    for (int m = 0; m < 4; ++m) {
      f32x4 acc = {0.f, 0.f, 0.f, 0.f};
#pragma unroll
      for (int k = 0; k < 4; ++k)
        acc = __builtin_amdgcn_mfma_f32_16x16x32_bf16(xf[m][k], gwf[k], acc, 0, 0, 0);
      sc[m] = acc;
    }
    __syncthreads();  // U-writes (rows lg*4+r) visible to uf-reads (rows l15)
    // sc += U @ gc^T (K padded to 32 with zeros)
    bf16x8 gcf = *(const bf16x8*)(gcp + lane * 8);
#pragma unroll
    for (int m = 0; m < 4; ++m) {
      bf16x8 uf = *(const bf16x8*)(Ulw + (m * 16 + l15) * 40 + lg * 8);
      sc[m] = __builtin_amdgcn_mfma_f32_16x16x32_bf16(uf, gcf, sc[m], 0, 0, 0);
    }
    // masked softmax over e (lane l15 = e)
    int b = tokw >> 12;
    float am = (l15 < 8 && active[b * 8 + l15] != 0) ? 0.f : -3.0e38f;
#pragma unroll
    for (int m = 0; m < 4; ++m) {
      f32x4 w4;
#pragma unroll
      for (int r = 0; r < 4; ++r) {
        float s = sc[m][r] + am;
        float mx = s;
        mx = fmaxf(mx, __shfl_xor(mx, 1));
        mx = fmaxf(mx, __shfl_xor(mx, 2));
        mx = fmaxf(mx, __shfl_xor(mx, 4));
        float p = __expf(s - mx);
        float su = p;
        su += __shfl_xor(su, 1);
        su += __shfl_xor(su, 2);
        su += __shfl_xor(su, 4);
        w4[r] = p / su;
      }
      wreg[m] = w4;
    }
  }

  // ---- expert loop: barrier-free, register double-buffered weights ----
  f32x4 acc2[4][8];
#pragma unroll
  for (int m = 0; m < 4; ++m)
#pragma unroll
    for (int o = 0; o < 8; ++o)
      acc2[m][o] = {0.f, 0.f, 0.f, 0.f};

  for (int e = 0; e < 8; ++e) {
    // wv[m] = w[token=l15 (+m*16)][e]; source lane ((l15>>2)<<4)|e, reg l15&3
    float wv[4];
    {
      int srcb = ((l15 >> 2) << 4) | e;
      int rp = l15 & 3;
#pragma unroll
      for (int m = 0; m < 4; ++m) {
        float q0 = __shfl(wreg[m][0], srcb), q1 = __shfl(wreg[m][1], srcb);
        float q2 = __shfl(wreg[m][2], srcb), q3 = __shfl(wreg[m][3], srcb);
        float lo = (rp & 1) ? q1 : q0, hi = (rp & 1) ? q3 : q2;
        wv[m] = (rp & 2) ? hi : lo;
      }
    }
    const short* w1e = W1p + e * 32768 + lane * 8;
    const short* w2e = W2p + e * 32768 + lane * 8;

    bf16x8 A1a[8], B2a[8], A1b[8], B2b[8];

    auto loadc = [&](bf16x8 (&A)[8], bf16x8 (&B)[8], int ks) {
#pragma unroll
      for (int i = 0; i < 8; ++i) {
        A[i] = *(const bf16x8*)(w1e + (ks * 8 + i) * 512);  // G1 frags (n*4+kx)
        B[i] = *(const bf16x8*)(w2e + (i * 8 + ks) * 512);  // G2 frags per o
      }
    };
    auto computec = [&](const bf16x8 (&A)[8], const bf16x8 (&B)[8]) {
      // G1: D[hid][token] for this 32-hid chunk (2 hid-tiles x K=128)
      f32x4 a1[4][2];
#pragma unroll
      for (int m = 0; m < 4; ++m)
#pragma unroll
        for (int n = 0; n < 2; ++n) {
          f32x4 acc = {0.f, 0.f, 0.f, 0.f};
#pragma unroll
          for (int kx = 0; kx < 4; ++kx)
            acc = __builtin_amdgcn_mfma_f32_16x16x32_bf16(A[n * 4 + kx], xf[m][kx], acc, 0, 0, 0);
          a1[m][n] = acc;
        }
      // pack: lane's 8 H values (token=l15) -> G2 B-frag in permuted k-order
      bf16x8 hB[4];
#pragma unroll
      for (int m = 0; m < 4; ++m) {
        bf16x8 h;
#pragma unroll
        for (int r = 0; r < 4; ++r) {
          h[r]     = f2bs(fmaxf(a1[m][0][r], 0.f) * wv[m]);
          h[r + 4] = f2bs(fmaxf(a1[m][1][r], 0.f) * wv[m]);
        }
        hB[m] = h;
      }
      // G2: acc2[m][o] += mfma(W2frag[o][ks], hB[m])  (D[out][token])
#pragma unroll
      for (int o = 0; o < 8; ++o)
#pragma unroll
        for (int m = 0; m < 4; ++m)
          acc2[m][o] = __builtin_amdgcn_mfma_f32_16x16x32_bf16(B[o], hB[m], acc2[m][o], 0, 0, 0);
    };

    loadc(A1a, B2a, 0);
#pragma unroll
    for (int kk = 0; kk < 4; ++kk) {
      loadc(A1b, B2b, 2 * kk + 1);   // prefetch odd chunk
      computec(A1a, B2a);            // compute even chunk
      if (kk < 3) loadc(A1a, B2a, 2 * kk + 2);  // prefetch next even
      computec(A1b, B2b);            // compute odd chunk
    }
  }

  // ---- direct stores: lane holds out = o*16+lg*4..+3, token = l15 (+m*16) ----
#pragma unroll
  for (int m = 0; m < 4; ++m)
#pragma unroll
    for (int o = 0; o < 8; ++o)
      *(f32x4*)(out + (size_t)(tokw + m * 16 + l15) * 128 + o * 16 + lg * 4) = acc2[m][o];

  if (blockIdx.x == 0 && tid == 0) out[8388608] = 0.0f;  // aux_loss
}

extern "C" void kernel_launch(void* const* d_in, const int* in_sizes, int n_in,
                              void* d_out, int out_size, void* d_ws, size_t ws_size,
                              hipStream_t stream) {
  const float* x      = (const float*)d_in[0];
  const int*   act    = (const int*)d_in[1];
  const float* sg_w1  = (const float*)d_in[2];
  const float* sg_w2  = (const float*)d_in[3];
  const float* gate_w = (const float*)d_in[4];
  const float* exp_w1 = (const float*)d_in[5];
  const float* exp_w2 = (const float*)d_in[6];
  short* ws_s = (short*)d_ws;
  float* out = (float*)d_out;

  prep_kernel<<<2066, 256, 0, stream>>>(sg_w1, sg_w2, gate_w, exp_w1, exp_w2, ws_s);
  moe_kernel<<<256, 256, 0, stream>>>(x, act, ws_s, out);
}